// Round 3
// baseline (385.633 us; speedup 1.0000x reference)
//
#include <hip/hip_runtime.h>

#define TT 128
#define SS 512
#define START_TAG 126
#define STOP_TAG 127
#define LOG2E 1.4426950408889634f
#define LN2   0.6931471805599453f

typedef float f32x4 __attribute__((ext_vector_type(4)));
typedef __fp16 f16x8 __attribute__((ext_vector_type(8)));
typedef __fp16 h2    __attribute__((ext_vector_type(2)));
typedef unsigned int u32;
typedef unsigned int u32x2 __attribute__((ext_vector_type(2)));
typedef unsigned int u32x4 __attribute__((ext_vector_type(4)));

__device__ __forceinline__ float ex2(float x) { return __builtin_amdgcn_exp2f(x); }   // 2^x
__device__ __forceinline__ float lg2(float x) { return __builtin_amdgcn_logf(x); }    // log2
__device__ __forceinline__ float exn(float x) { return __builtin_amdgcn_exp2f(x * LOG2E); } // e^x

__device__ __forceinline__ float wave_max(float v) {
#pragma unroll
    for (int off = 32; off >= 1; off >>= 1) v = fmaxf(v, __shfl_xor(v, off));
    return v;
}
__device__ __forceinline__ float wave_sum(float v) {
#pragma unroll
    for (int off = 32; off >= 1; off >>= 1) v += __shfl_xor(v, off);
    return v;
}

// ---------------- pre-pass: ef[b][s][tag] = (f16) exp(feats) ----------------
__global__ __launch_bounds__(256) void exp_feats_kernel(
    const float* __restrict__ feats, __fp16* __restrict__ ef)
{
    size_t i = ((size_t)blockIdx.x * 256 + threadIdx.x) * 8;
    f32x4 a = *(const f32x4*)(feats + i);
    f32x4 b = *(const f32x4*)(feats + i + 4);
    h2 r0 = __builtin_amdgcn_cvt_pkrtz(exn(a[0]), exn(a[1]));
    h2 r1 = __builtin_amdgcn_cvt_pkrtz(exn(a[2]), exn(a[3]));
    h2 r2 = __builtin_amdgcn_cvt_pkrtz(exn(b[0]), exn(b[1]));
    h2 r3 = __builtin_amdgcn_cvt_pkrtz(exn(b[2]), exn(b[3]));
    u32x4 pk;
    pk[0] = __builtin_bit_cast(u32, r0);
    pk[1] = __builtin_bit_cast(u32, r1);
    pk[2] = __builtin_bit_cast(u32, r2);
    pk[3] = __builtin_bit_cast(u32, r3);
    *(u32x4*)(ef + i) = pk;
}

// ---------------- ef load (depth-4 pipeline buffer) ----------------
// Buffer tt holds ef[tags 16tt+4h .. +3] as 2 packed u32 (matches D rows).
template<bool PRE>
__device__ __forceinline__ void load_ef(const char*& pef, int sstep, u32x2 (&d)[8])
{
    if constexpr (PRE) {
#pragma unroll
        for (int tt = 0; tt < 8; ++tt) d[tt] = *(const u32x2*)(pef + 32 * tt);
    } else {
#pragma unroll
        for (int tt = 0; tt < 8; ++tt) {
            f32x4 v = *(const f32x4*)(pef + 64 * tt);
            h2 a = __builtin_amdgcn_cvt_pkrtz(exn(v[0]), exn(v[1]));
            h2 b = __builtin_amdgcn_cvt_pkrtz(exn(v[2]), exn(v[3]));
            d[tt][0] = __builtin_bit_cast(u32, a);
            d[tt][1] = __builtin_bit_cast(u32, b);
        }
    }
    pef += sstep;
}

// ---------------- one recurrence step for 16 chains ----------------
// k-map (shared by A-init, seed, and B-formation):
//   k(q,h,j) = 32q + 16*(j>=4) + 4h + (j&3)
// Valid because MFMA pairs A(h,j) with B(h,j); any consistent bijection works.
// Scale: exact 2^-s, s from tile-0 column max (current step, zero lag ->
// unconditionally stable); integer-exact bookkeeping in Mint.
__device__ __forceinline__ void chain_step(
    const f16x8 (&E)[8][4], f16x8 (&Bv)[4], const u32x2 (&ef)[8], int& Mint)
{
    const f32x4 z = {0.f, 0.f, 0.f, 0.f};
    // tile 0 first: its colmax drives the scale, computed under the other MFMAs
    f32x4 a0 = __builtin_amdgcn_mfma_f32_16x16x32_f16(E[0][0], Bv[0], z, 0, 0, 0);
    a0 = __builtin_amdgcn_mfma_f32_16x16x32_f16(E[0][1], Bv[1], a0, 0, 0, 0);
    a0 = __builtin_amdgcn_mfma_f32_16x16x32_f16(E[0][2], Bv[2], a0, 0, 0, 0);
    a0 = __builtin_amdgcn_mfma_f32_16x16x32_f16(E[0][3], Bv[3], a0, 0, 0, 0);

    float m01 = fmaxf(fmaxf(a0[0], a0[1]), fmaxf(a0[2], a0[3]));
    m01 = fmaxf(m01, __shfl_xor(m01, 16));
    m01 = fmaxf(m01, __shfl_xor(m01, 32));          // column max over the 4 h-lanes
    int s = ((__float_as_int(m01) >> 23) & 0xff) - 125;   // m*2^-s in [0.25, 0.5)
    s = s < -120 ? -120 : (s > 120 ? 120 : s);
    Mint += s;
    const float scf = __int_as_float((127 - s) << 23);    // exact 2^-s

    f32x4 acc[8];
    acc[0] = a0;
#pragma unroll
    for (int tt = 1; tt < 8; ++tt)
        acc[tt] = __builtin_amdgcn_mfma_f32_16x16x32_f16(E[tt][0], Bv[0], z, 0, 0, 0);
#pragma unroll
    for (int q = 1; q < 4; ++q)
#pragma unroll
        for (int tt = 1; tt < 8; ++tt)
            acc[tt] = __builtin_amdgcn_mfma_f32_16x16x32_f16(E[tt][q], Bv[q], acc[tt], 0, 0, 0);

    u32 pp[8][2];
#pragma unroll
    for (int tt = 0; tt < 8; ++tt) {
        h2 p01 = __builtin_amdgcn_cvt_pkrtz(acc[tt][0] * scf, acc[tt][1] * scf);
        h2 p23 = __builtin_amdgcn_cvt_pkrtz(acc[tt][2] * scf, acc[tt][3] * scf);
        p01 *= __builtin_bit_cast(h2, ef[tt][0]);   // emission, packed f16
        p23 *= __builtin_bit_cast(h2, ef[tt][1]);
        pp[tt][0] = __builtin_bit_cast(u32, p01);
        pp[tt][1] = __builtin_bit_cast(u32, p23);
    }
    // B formation: pure register re-pack, no cross-lane movement (by k-map choice)
#pragma unroll
    for (int q = 0; q < 4; ++q) {
        u32x4 bv = { pp[2 * q][0], pp[2 * q][1], pp[2 * q + 1][0], pp[2 * q + 1][1] };
        Bv[q] = __builtin_bit_cast(f16x8, bv);
    }
}

// 8 blocks x 256 threads. Block k: batches 32k..32k+31.
//  w0: fwd chains (batches +0..15)  w1: fwd (+16..31)
//  w2: bwd chains (+0..15)          w3: bwd (+16..31)
template<bool PRE>
__global__ __launch_bounds__(256, 1) void crf_chain_kernel(
    const float* __restrict__ feats,
    const float* __restrict__ trans,
    const int*   __restrict__ targets,
    const __fp16* __restrict__ efeat,
    float*       __restrict__ out)
{
    const int t = threadIdx.x;
    const int w = t >> 6, l = t & 63;
    const int c = l & 15, h = l >> 4;
    const int base = blockIdx.x * 32;
    const int bb = (w & 1) * 16 + c;          // block-local batch 0..31
    const int batch = base + bb;
    const bool isFwd = (w >> 1) == 0;
    const int side = isFwd ? 0 : 1;

    __shared__ __align__(16) float AB[2][32][TT];   // final log2-states
    __shared__ float salpha[32];
    __shared__ float gpart[32][8];

    // ---- E fragments: A[row=16tt+c][k(q,h,j)] ----
    f16x8 E[8][4];
#pragma unroll
    for (int tt = 0; tt < 8; ++tt) {
        const int ro = 16 * tt + c;
#pragma unroll
        for (int q = 0; q < 4; ++q) {
            f16x8 F;
            if (isFwd) {
                f32x4 t0 = *(const f32x4*)(trans + ro * TT + 32 * q + 4 * h);
                f32x4 t1 = *(const f32x4*)(trans + ro * TT + 32 * q + 16 + 4 * h);
#pragma unroll
                for (int j = 0; j < 4; ++j) {
                    F[j]     = (__fp16)exn(t0[j]);
                    F[j + 4] = (__fp16)exn(t1[j]);
                }
            } else {
#pragma unroll
                for (int j = 0; j < 8; ++j) {
                    const int k = 32 * q + ((j & 4) << 2) + 4 * h + (j & 3);
                    F[j] = (__fp16)exn(trans[k * TT + ro]);   // E^T
                }
            }
            E[tt][q] = F;
        }
    }

    // ---- seed B (same k-map) ----
    f16x8 Bv[4];
#pragma unroll
    for (int q = 0; q < 4; ++q) {
#pragma unroll
        for (int j = 0; j < 8; ++j) {
            const int k = 32 * q + ((j & 4) << 2) + 4 * h + (j & 3);
            float v;
            if (isFwd) v = (k == START_TAG) ? 1.f : 0.f;
            else       v = exn(trans[STOP_TAG * TT + k] +
                               feats[((size_t)batch * SS + 511) * TT + k]);
            Bv[q][j] = (__fp16)v;
        }
    }

    // ---- emission pointer ----
    const char* pef;
    int sstep;
    if constexpr (PRE) {
        pef = (const char*)efeat + 2 * (((size_t)batch * SS + (isFwd ? 0 : 510)) * TT) + 8 * h;
        sstep = isFwd ? (TT * 2) : -(TT * 2);
    } else {
        pef = (const char*)feats + 4 * (((size_t)batch * SS + (isFwd ? 0 : 510)) * TT) + 16 * h;
        sstep = isFwd ? (TT * 4) : -(TT * 4);
    }

    int Mint = 0;
    u32x2 e0[8], e1[8], e2[8], e3[8];
    load_ef<PRE>(pef, sstep, e0);             // pos 0 (fwd) / 510 (bwd)
    load_ef<PRE>(pef, sstep, e1);
    load_ef<PRE>(pef, sstep, e2);
    load_ef<PRE>(pef, sstep, e3);
#pragma unroll 1
    for (int it = 0; it < 62; ++it) {         // steps 0..247
        chain_step(E, Bv, e0, Mint); load_ef<PRE>(pef, sstep, e0);
        chain_step(E, Bv, e1, Mint); load_ef<PRE>(pef, sstep, e1);
        chain_step(E, Bv, e2, Mint); load_ef<PRE>(pef, sstep, e2);
        chain_step(E, Bv, e3, Mint); load_ef<PRE>(pef, sstep, e3);
    }
    chain_step(E, Bv, e0, Mint); load_ef<PRE>(pef, sstep, e0);   // 248 / load 252
    chain_step(E, Bv, e1, Mint); load_ef<PRE>(pef, sstep, e1);   // 249 / 253
    chain_step(E, Bv, e2, Mint); load_ef<PRE>(pef, sstep, e2);   // 250 / 254
    chain_step(E, Bv, e3, Mint); load_ef<PRE>(pef, sstep, e3);   // 251 / 255
    chain_step(E, Bv, e0, Mint);                                  // 252
    chain_step(E, Bv, e1, Mint);                                  // 253
    chain_step(E, Bv, e2, Mint);                                  // 254
    // 255th multiply = epilogue (fwd folds ef_255 in log space; bwd none)

    const f32x4 z = {0.f, 0.f, 0.f, 0.f};
    f32x4 acc[8];
#pragma unroll
    for (int tt = 0; tt < 8; ++tt)
        acc[tt] = __builtin_amdgcn_mfma_f32_16x16x32_f16(E[tt][0], Bv[0], z, 0, 0, 0);
#pragma unroll
    for (int q = 1; q < 4; ++q)
#pragma unroll
        for (int tt = 0; tt < 8; ++tt)
            acc[tt] = __builtin_amdgcn_mfma_f32_16x16x32_f16(E[tt][q], Bv[q], acc[tt], 0, 0, 0);

    const float Mtotf = (float)Mint;
#pragma unroll
    for (int tt = 0; tt < 8; ++tt) {
        float ev0 = 1.f, ev1 = 1.f, ev2 = 1.f, ev3 = 1.f;
        if (isFwd) {
            h2 a = __builtin_bit_cast(h2, e3[tt][0]);
            h2 b = __builtin_bit_cast(h2, e3[tt][1]);
            ev0 = (float)a[0]; ev1 = (float)a[1]; ev2 = (float)b[0]; ev3 = (float)b[1];
        }
        f32x4 v;
        v[0] = Mtotf + lg2(fmaxf(acc[tt][0] * ev0, 1e-35f));
        v[1] = Mtotf + lg2(fmaxf(acc[tt][1] * ev1, 1e-35f));
        v[2] = Mtotf + lg2(fmaxf(acc[tt][2] * ev2, 1e-35f));
        v[3] = Mtotf + lg2(fmaxf(acc[tt][3] * ev3, 1e-35f));
        *(f32x4*)&AB[side][bb][16 * tt + 4 * h] = v;   // D rows are true tag indices
    }
    __syncthreads();

    // ---- Z = LSE_tag(A + B) (log2 domain), 8 batches per wave ----
#pragma unroll 1
    for (int k8 = 0; k8 < 8; ++k8) {
        const int bq = w * 8 + k8;
        float v0 = AB[0][bq][l] + AB[1][bq][l];
        float v1 = AB[0][bq][l + 64] + AB[1][bq][l + 64];
        float mm = wave_max(fmaxf(v0, v1));
        float ss = wave_sum(ex2(v0 - mm) + ex2(v1 - mm));
        if (l == 0) salpha[bq] = (mm + lg2(ss)) * LN2;
    }

    // ---- gold path score: 8 threads per batch, 64 steps each ----
    {
        const int bbg = t & 31, ck = t >> 5;
        const int gb  = base + bbg;
        const int* tg = targets + gb * SS;
        const float* fb = feats + (size_t)gb * SS * TT;
        float gs = 0.f;
        const int i0 = ck * 64;
        int prev = (i0 == 0) ? START_TAG : tg[i0 - 1];
        for (int i = i0; i < i0 + 64; ++i) {
            int cur = tg[i];
            gs += trans[cur * TT + prev] + fb[(size_t)i * TT + cur];
            prev = cur;
        }
        if (ck == 7) gs += trans[STOP_TAG * TT + tg[SS - 1]];
        gpart[bbg][ck] = gs;
    }
    __syncthreads();

    if (t < 32) {
        float g = 0.f;
#pragma unroll
        for (int k = 0; k < 8; ++k) g += gpart[t][k];
        out[base + t] = g - salpha[t];
    }
}

extern "C" void kernel_launch(void* const* d_in, const int* in_sizes, int n_in,
                              void* d_out, int out_size, void* d_ws, size_t ws_size,
                              hipStream_t stream) {
    (void)in_sizes; (void)n_in; (void)out_size;
    const float* feats   = (const float*)d_in[0];
    const float* trans   = (const float*)d_in[1];
    const int*   targets = (const int*)d_in[2];
    float*       out     = (float*)d_out;

    const size_t efbytes = (size_t)256 * SS * TT * sizeof(__fp16);  // 33.5 MB
    if (d_ws && ws_size >= efbytes) {
        __fp16* ef = (__fp16*)d_ws;
        exp_feats_kernel<<<dim3(8192), dim3(256), 0, stream>>>(feats, ef);
        crf_chain_kernel<true><<<dim3(8), dim3(256), 0, stream>>>(feats, trans, targets, ef, out);
    } else {
        crf_chain_kernel<false><<<dim3(8), dim3(256), 0, stream>>>(feats, trans, targets,
                                                                   (const __fp16*)nullptr, out);
    }
}